// Round 18
// baseline (94.671 us; speedup 1.0000x reference)
//
#include <hip/hip_runtime.h>
#include <math.h>

#define N_NODES 100000
#define N_EDGES 1600000
#define C 64
#define BKT_SHIFT 6
#define BKT_NODES 64          // nodes per bucket
#define NBKT 1563             // ceil(100000/64)
#define TILE 8192             // edges per tile
#define NBINB 196             // ceil(N_EDGES/TILE)
#define NGEMB 391             // ceil(N_NODES/256)
#define PSTR 1564             // tab row stride (NBKT + 1)
#define TSTR 200              // tabT row stride (NBINB padded)
#define LUTN 2048             // per-bucket edge capacity
#define MAXW 65               // LDS row stride (64 + 1 pad; 2-way = free)
#define NSTRIPE 32
#define XSTR 72               // LDS ushort row stride for W staging
#define BN_EPS 1e-5f

typedef __attribute__((ext_vector_type(8))) short short8;
typedef __attribute__((ext_vector_type(4))) float f32x4;

// ws layout:
//   Bkey   : N*32 u32 (bf16 key-packed x@W2)     12.8 MB
//   binned : NBINB*TILE u32 (tile-major, bucket-sorted within tile)  6.4 MB
//   Apb    : N*32 u32 (bf16-packed A')           12.8 MB
//   hpk    : N*32 u32 (bf16-packed h)            12.8 MB
//   tab    : NBINB*PSTR u32 (per-tile exclusive prefix)   1.23 MB
//   tabT   : NBKT*TSTR u32 ((len<<16)|rstart per (bucket,tile))  1.25 MB
//   stripes: NSTRIPE*128 floats; finals: 128 floats

__device__ __forceinline__ float eluf(float x) {
    return x > 0.f ? x : (expf(x) - 1.f);
}
__device__ __forceinline__ float key32_to_f(unsigned k32) {
    unsigned k16 = k32 >> 16;
    unsigned u16 = (k16 & 0x8000u) ? (k16 & 0x7FFFu) : (~k16 & 0xFFFFu);
    return __uint_as_float(u16 << 16);
}
__device__ __forceinline__ unsigned bf16rne(float f) {
    unsigned u = __float_as_uint(f);
    return (u + 0x7FFFu + ((u >> 16) & 1u)) >> 16;
}
__device__ __forceinline__ float bf16lo_f(unsigned w) { return __uint_as_float((w & 0xFFFFu) << 16); }
__device__ __forceinline__ float bf16hi_f(unsigned w) { return __uint_as_float(w & 0xFFFF0000u); }

__device__ __forceinline__ short8 pack8(float4 a, float4 b) {
    short8 r;
    r[0] = (short)bf16rne(a.x); r[1] = (short)bf16rne(a.y);
    r[2] = (short)bf16rne(a.z); r[3] = (short)bf16rne(a.w);
    r[4] = (short)bf16rne(b.x); r[5] = (short)bf16rne(b.y);
    r[6] = (short)bf16rne(b.z); r[7] = (short)bf16rne(b.w);
    return r;
}

// Per-tile histogram + exclusive prefix -> tab row. Block 0 also zeroes stripes.
__global__ __launch_bounds__(1024) void k_hist(const int* __restrict__ ei,
                                               unsigned* __restrict__ tab,
                                               float* __restrict__ stripes) {
    __shared__ unsigned hc[NBKT];
    __shared__ unsigned ss[1024];
    int t = threadIdx.x;
    int tile = blockIdx.x;
    int e0 = tile * TILE;
    int ecount = min(TILE, N_EDGES - e0);

    for (int i = t; i < NBKT; i += 1024) hc[i] = 0u;
    if (blockIdx.x == 0) {
        for (int i = t; i < NSTRIPE * 128; i += 1024) stripes[i] = 0.f;
    }
    __syncthreads();
    for (int i = t; i < ecount; i += 1024) {
        int src = ei[e0 + i];
        int dst = ei[N_EDGES + e0 + i];
        if ((unsigned)src < N_NODES && (unsigned)dst < N_NODES)
            atomicAdd(&hc[dst >> BKT_SHIFT], 1u);
    }
    __syncthreads();
    unsigned v0 = (2 * t < NBKT) ? hc[2 * t] : 0u;
    unsigned v1 = (2 * t + 1 < NBKT) ? hc[2 * t + 1] : 0u;
    unsigned s = v0 + v1;
    ss[t] = s;
    __syncthreads();
    for (int off = 1; off < 1024; off <<= 1) {
        unsigned v = (t >= off) ? ss[t - off] : 0u;
        __syncthreads();
        ss[t] += v;
        __syncthreads();
    }
    unsigned excl = ss[t] - s;
    unsigned* row = tab + (size_t)tile * PSTR;
    if (2 * t < NBKT) row[2 * t] = excl;
    if (2 * t + 1 < NBKT) row[2 * t + 1] = excl + v0;
    if (t == 1023) row[NBKT] = ss[1023];
}

// tab[tile][bucket] -> tabT[bucket][tile] = (len<<16)|rstart.
// Writes coalesced; reads strided but L2-resident (tab = 1.23 MB).
__global__ __launch_bounds__(256) void k_transpose(const unsigned* __restrict__ tab,
                                                   unsigned* __restrict__ tabT) {
    int idx = blockIdx.x * 256 + threadIdx.x;
    if (idx >= NBKT * NBINB) return;
    int q = idx / NBINB;
    int t = idx - q * NBINB;
    unsigned rs = tab[(size_t)t * PSTR + q];
    unsigned re = tab[(size_t)t * PSTR + q + 1];
    tabT[(size_t)q * TSTR + t] = ((re - rs) << 16) | rs;
}

// Fused prep: blocks [0,NBINB) place edges (no global atomics, amp~1);
// blocks [NBINB,..) do the MFMA GEMM.
__global__ __launch_bounds__(1024) void k_prep(const int* __restrict__ ei,
                                               const float* __restrict__ x,
                                               const float* __restrict__ W,
                                               const float* __restrict__ b,
                                               const unsigned* __restrict__ tab,
                                               unsigned* __restrict__ binned,
                                               unsigned* __restrict__ Apb,
                                               unsigned* __restrict__ Bkey) {
    __shared__ __align__(16) unsigned char smem[18688];
    int t = threadIdx.x;

    if (blockIdx.x < NBINB) {
        unsigned* cur = (unsigned*)smem;
        int tile = blockIdx.x;
        int e0 = tile * TILE;
        int ecount = min(TILE, N_EDGES - e0);
        const unsigned* row = tab + (size_t)tile * PSTR;
        for (int i = t; i < NBKT; i += 1024) cur[i] = row[i];
        __syncthreads();
        for (int i = t; i < ecount; i += 1024) {
            int src = ei[e0 + i];
            int dst = ei[N_EDGES + e0 + i];
            if ((unsigned)src >= N_NODES || (unsigned)dst >= N_NODES) continue;
            int bk = dst >> BKT_SHIFT;
            unsigned pos = atomicAdd(&cur[bk], 1u);
            binned[(size_t)tile * TILE + pos] =
                ((unsigned)(dst & (BKT_NODES - 1)) << 17) | (unsigned)src;
        }
    } else {
        unsigned short* WaT = (unsigned short*)smem;
        unsigned short* WbT = WaT + 64 * XSTR;
        float* biasS = (float*)(WbT + 64 * XSTR);
        int gb = blockIdx.x - NBINB;
        int base = gb * 256;

        for (int p = t; p < 4096; p += 1024) {
            int k = p >> 6, c = p & 63;
            float w1 = W[p];
            float w2 = W[4096 + p];
            WaT[c * XSTR + k] = (unsigned short)bf16rne(w1 - w2);
            WbT[c * XSTR + k] = (unsigned short)bf16rne(w2);
        }
        if (t < 64) biasS[t] = b[t];
        __syncthreads();

        int w = t >> 6;
        int l = t & 63;
        int ln = l & 15;
        int hi = l >> 4;

        short8 wa[4][2], wb[4][2];
#pragma unroll
        for (int nt = 0; nt < 4; ++nt)
#pragma unroll
            for (int h = 0; h < 2; ++h) {
                wa[nt][h] = *(const short8*)&WaT[(nt * 16 + ln) * XSTR + h * 32 + hi * 8];
                wb[nt][h] = *(const short8*)&WbT[(nt * 16 + ln) * XSTR + h * 32 + hi * 8];
            }

        int arow = base + w * 16 + ln;
        short8 af[2];
        if (arow < N_NODES) {
            const float4* xr = (const float4*)(x + (size_t)arow * 64);
#pragma unroll
            for (int h = 0; h < 2; ++h)
                af[h] = pack8(xr[h * 8 + hi * 2], xr[h * 8 + hi * 2 + 1]);
        } else {
#pragma unroll
            for (int h = 0; h < 2; ++h)
                af[h] = (short8){0, 0, 0, 0, 0, 0, 0, 0};
        }

        f32x4 acca[4], accb[4];
#pragma unroll
        for (int nt = 0; nt < 4; ++nt) {
            acca[nt] = (f32x4){0.f, 0.f, 0.f, 0.f};
            accb[nt] = (f32x4){0.f, 0.f, 0.f, 0.f};
#pragma unroll
            for (int h = 0; h < 2; ++h) {
                acca[nt] = __builtin_amdgcn_mfma_f32_16x16x32_bf16(af[h], wa[nt][h], acca[nt], 0, 0, 0);
                accb[nt] = __builtin_amdgcn_mfma_f32_16x16x32_bf16(af[h], wb[nt][h], accb[nt], 0, 0, 0);
            }
        }
#pragma unroll
        for (int nt = 0; nt < 4; ++nt) {
            int col = nt * 16 + ln;
            float bias = biasS[col];
            int cp = nt * 8 + (ln >> 1);
#pragma unroll
            for (int r = 0; r < 4; ++r) {
                int node = base + w * 16 + hi * 4 + r;
                unsigned a16 = bf16rne(acca[nt][r] + bias);
                unsigned aO = (unsigned)__shfl_xor((int)a16, 1, 64);
                unsigned r16 = bf16rne(accb[nt][r]);
                unsigned key16 = (r16 & 0x8000u) ? (~r16 & 0xFFFFu) : (r16 | 0x8000u);
                unsigned kO = (unsigned)__shfl_xor((int)key16, 1, 64);
                if (((l & 1) == 0) && node < N_NODES) {
                    Apb[(size_t)node * 32 + cp] = a16 | (aO << 16);
                    Bkey[(size_t)node * 32 + cp] = key16 | (kO << 16);
                }
            }
        }
    }
}

// One bucket per block (XCD-chunked swizzle). Coalesced tabT row load, scan
// lengths, build direct LDS LUT (addr base per edge idx) -> 1 LDS read/edge.
// Gather 4 lanes/edge (2 coalesced 64B lines), LDS atomicMax, finish + BN.
__global__ __launch_bounds__(256) void k_fused(const unsigned* __restrict__ tabT,
                                               const unsigned* __restrict__ binned,
                                               const unsigned* __restrict__ Bkey,
                                               const unsigned* __restrict__ Apb,
                                               unsigned* __restrict__ hpk,
                                               float* __restrict__ stripes) {
    __shared__ __align__(16) unsigned mx[BKT_NODES * MAXW];  // 16640 B
    __shared__ unsigned lut[LUTN];                           // 8192 B
    __shared__ unsigned rb[256];
    int t = threadIdx.x;
    // bijective XCD-chunked swizzle (nwg=1563, 8 XCDs, r=3)
    int orig = blockIdx.x;
    int xcd = orig & 7;
    int j = orig >> 3;
    int q = (xcd < 3 ? xcd * 196 : 3 * 196 + (xcd - 3) * 195) + j;
    int n0 = q * BKT_NODES;
    int nspan = min(BKT_NODES, N_NODES - n0);

    for (int i = t; i < BKT_NODES * MAXW; i += 256) mx[i] = 0u;

    // coalesced tabT row load: (len<<16)|rstart per tile
    unsigned e = (t < NBINB) ? tabT[(size_t)q * TSTR + t] : 0u;
    unsigned rs = e & 0xFFFFu;
    unsigned len = e >> 16;
    rb[t] = len;
    __syncthreads();
    for (int off = 1; off < 256; off <<= 1) {
        unsigned v = (t >= off) ? rb[t - off] : 0u;
        __syncthreads();
        rb[t] += v;
        __syncthreads();
    }
    unsigned incl = rb[t];
    unsigned excl = incl - len;
    unsigned cnt = min(rb[255], (unsigned)LUTN);
    __syncthreads();
    // build LUT: lut[idx] = tile*TILE + rstart - excl  for idx in [excl, excl+len)
    if (t < NBINB && len) {
        unsigned base = (unsigned)t * TILE + rs - excl;
        unsigned jend = min(excl + len, (unsigned)LUTN);
        for (unsigned ji = excl; ji < jend; ++ji) lut[ji] = base;
    }
    __syncthreads();

    int ls = t & 3;
    for (unsigned idx = (unsigned)(t >> 2); idx < cnt; idx += 64) {
        unsigned p = binned[(size_t)(lut[idx] + idx)];
        unsigned src = p & 0x1FFFFu;
        unsigned dl = p >> 17;
        const uint4* bk = (const uint4*)(Bkey + (size_t)src * 32);
        uint4 w0 = bk[ls];
        uint4 w1 = bk[4 + ls];
        unsigned* row = mx + dl * MAXW;
        int s0 = ls * 8;
        atomicMax(&row[s0 + 0], w0.x << 16);
        atomicMax(&row[s0 + 1], w0.x & 0xFFFF0000u);
        atomicMax(&row[s0 + 2], w0.y << 16);
        atomicMax(&row[s0 + 3], w0.y & 0xFFFF0000u);
        atomicMax(&row[s0 + 4], w0.z << 16);
        atomicMax(&row[s0 + 5], w0.z & 0xFFFF0000u);
        atomicMax(&row[s0 + 6], w0.w << 16);
        atomicMax(&row[s0 + 7], w0.w & 0xFFFF0000u);
        int s1 = 32 + ls * 8;
        atomicMax(&row[s1 + 0], w1.x << 16);
        atomicMax(&row[s1 + 1], w1.x & 0xFFFF0000u);
        atomicMax(&row[s1 + 2], w1.y << 16);
        atomicMax(&row[s1 + 3], w1.y & 0xFFFF0000u);
        atomicMax(&row[s1 + 4], w1.z << 16);
        atomicMax(&row[s1 + 5], w1.z & 0xFFFF0000u);
        atomicMax(&row[s1 + 6], w1.w << 16);
        atomicMax(&row[s1 + 7], w1.w & 0xFFFF0000u);
    }
    __syncthreads();

    int lane4 = t & 15;
    int g = t >> 4;
    float4 s = make_float4(0.f, 0.f, 0.f, 0.f);
    float4 sq = make_float4(0.f, 0.f, 0.f, 0.f);
    for (int nl = g; nl < nspan; nl += 16) {
        int n = n0 + nl;
        const unsigned* row = mx + nl * MAXW + lane4 * 4;
        unsigned k0 = row[0], k1 = row[1], k2 = row[2], k3 = row[3];
        uint2 ap = *reinterpret_cast<const uint2*>(Apb + (size_t)n * 32 + lane4 * 2);
        float h0 = (k0 == 0u) ? 0.f : eluf(bf16lo_f(ap.x) + key32_to_f(k0));
        float h1 = (k1 == 0u) ? 0.f : eluf(bf16hi_f(ap.x) + key32_to_f(k1));
        float h2 = (k2 == 0u) ? 0.f : eluf(bf16lo_f(ap.y) + key32_to_f(k2));
        float h3 = (k3 == 0u) ? 0.f : eluf(bf16hi_f(ap.y) + key32_to_f(k3));
        unsigned q0 = bf16rne(h0), q1 = bf16rne(h1), q2 = bf16rne(h2), q3 = bf16rne(h3);
        uint2 hp;
        hp.x = q0 | (q1 << 16);
        hp.y = q2 | (q3 << 16);
        *reinterpret_cast<uint2*>(hpk + (size_t)n * 32 + lane4 * 2) = hp;
        float f0 = __uint_as_float(q0 << 16), f1 = __uint_as_float(q1 << 16);
        float f2 = __uint_as_float(q2 << 16), f3 = __uint_as_float(q3 << 16);
        s.x += f0; s.y += f1; s.z += f2; s.w += f3;
        sq.x += f0 * f0; sq.y += f1 * f1; sq.z += f2 * f2; sq.w += f3 * f3;
    }
    __syncthreads();

    float4* lsum = (float4*)mx;
    float4* lqum = lsum + 256;
    lsum[t] = s;
    lqum[t] = sq;
    __syncthreads();
#pragma unroll
    for (int off = 8; off >= 1; off >>= 1) {
        if (g < off) {
            int o = t + off * 16;
            lsum[t].x += lsum[o].x; lsum[t].y += lsum[o].y; lsum[t].z += lsum[o].z; lsum[t].w += lsum[o].w;
            lqum[t].x += lqum[o].x; lqum[t].y += lqum[o].y; lqum[t].z += lqum[o].z; lqum[t].w += lqum[o].w;
        }
        __syncthreads();
    }
    if (g == 0) {
        float* sb = stripes + (q & (NSTRIPE - 1)) * 128;
        int c4 = lane4 * 4;
        atomicAdd(&sb[c4 + 0], lsum[t].x);
        atomicAdd(&sb[c4 + 1], lsum[t].y);
        atomicAdd(&sb[c4 + 2], lsum[t].z);
        atomicAdd(&sb[c4 + 3], lsum[t].w);
        atomicAdd(&sb[64 + c4 + 0], lqum[t].x);
        atomicAdd(&sb[64 + c4 + 1], lqum[t].y);
        atomicAdd(&sb[64 + c4 + 2], lqum[t].z);
        atomicAdd(&sb[64 + c4 + 3], lqum[t].w);
    }
}

// fold 32 stripes -> 128 finals
__global__ __launch_bounds__(128) void k_reduce(const float* __restrict__ stripes,
                                                float* __restrict__ finals) {
    int t = threadIdx.x;
    float acc = 0.f;
#pragma unroll
    for (int s = 0; s < NSTRIPE; ++s) acc += stripes[s * 128 + t];
    finals[t] = acc;
}

// out = gamma*(h-mean)*rsqrt(var+eps)+beta; reads bf16-packed h, writes f32
__global__ __launch_bounds__(256) void k_bn(const uint2* __restrict__ hpk2,
                                            const float* __restrict__ finals,
                                            const float* __restrict__ gamma,
                                            const float* __restrict__ beta,
                                            float4* __restrict__ out4) {
    size_t i = (size_t)blockIdx.x * blockDim.x + threadIdx.x;
    size_t stride = (size_t)gridDim.x * blockDim.x;
    const float invN = 1.f / (float)N_NODES;
    size_t total4 = (size_t)N_NODES * C / 4;
    for (size_t p = i; p < total4; p += stride) {
        int c4 = (int)(p & 15) * 4;
        uint2 hp = hpk2[p];
        float hx = bf16lo_f(hp.x), hy = bf16hi_f(hp.x);
        float hz = bf16lo_f(hp.y), hw = bf16hi_f(hp.y);
        float4 o;
        float m, v, inv;
        m = finals[c4 + 0] * invN; v = finals[64 + c4 + 0] * invN - m * m; inv = rsqrtf(v + BN_EPS);
        o.x = gamma[c4 + 0] * (hx - m) * inv + beta[c4 + 0];
        m = finals[c4 + 1] * invN; v = finals[64 + c4 + 1] * invN - m * m; inv = rsqrtf(v + BN_EPS);
        o.y = gamma[c4 + 1] * (hy - m) * inv + beta[c4 + 1];
        m = finals[c4 + 2] * invN; v = finals[64 + c4 + 2] * invN - m * m; inv = rsqrtf(v + BN_EPS);
        o.z = gamma[c4 + 2] * (hz - m) * inv + beta[c4 + 2];
        m = finals[c4 + 3] * invN; v = finals[64 + c4 + 3] * invN - m * m; inv = rsqrtf(v + BN_EPS);
        o.w = gamma[c4 + 3] * (hw - m) * inv + beta[c4 + 3];
        out4[p] = o;
    }
}

extern "C" void kernel_launch(void* const* d_in, const int* in_sizes, int n_in,
                              void* d_out, int out_size, void* d_ws, size_t ws_size,
                              hipStream_t stream) {
    const float* x = (const float*)d_in[0];
    const int* ei = (const int*)d_in[1];  // int32 per harness contract
    const float* W = (const float*)d_in[2];
    const float* b = (const float*)d_in[3];
    const float* gamma = (const float*)d_in[4];
    const float* beta = (const float*)d_in[5];
    float* out = (float*)d_out;

    char* ws = (char*)d_ws;
    unsigned* Bkey = (unsigned*)ws;                                      // 12.8 MB
    unsigned* binned = Bkey + (size_t)N_NODES * 32;                      // 6.43 MB
    unsigned* Apb = binned + (size_t)NBINB * TILE;                       // 12.8 MB
    unsigned* hpk = Apb + (size_t)N_NODES * 32;                          // 12.8 MB
    unsigned* tab = hpk + (size_t)N_NODES * 32;                          // 1.23 MB
    unsigned* tabT = tab + (size_t)NBINB * PSTR;                         // 1.25 MB
    float* stripes = (float*)(tabT + (size_t)NBKT * TSTR);
    float* finals = stripes + NSTRIPE * 128;

    k_hist<<<NBINB, 1024, 0, stream>>>(ei, tab, stripes);
    k_transpose<<<(NBKT * NBINB + 255) / 256, 256, 0, stream>>>(tab, tabT);
    k_prep<<<NBINB + NGEMB, 1024, 0, stream>>>(ei, x, W, b, tab, binned, Apb, Bkey);
    k_fused<<<NBKT, 256, 0, stream>>>(tabT, binned, Bkey, Apb, hpk, stripes);
    k_reduce<<<1, 128, 0, stream>>>(stripes, finals);
    k_bn<<<2048, 256, 0, stream>>>((const uint2*)hpk, finals, gamma, beta, (float4*)out);
}

// Round 19
// 82.670 us; speedup vs baseline: 1.1452x; 1.1452x over previous
//
#include <hip/hip_runtime.h>
#include <math.h>

#define N_NODES 100000
#define N_EDGES 1600000
#define C 64
#define BKT_SHIFT 6
#define BKT_NODES 64          // nodes per bucket
#define NBKT 1563             // ceil(100000/64)
#define TILE 8192             // edges per tile
#define NBINB 196             // ceil(N_EDGES/TILE)
#define NGEMB 391             // ceil(N_NODES/256)
#define PSTR 1564             // tab row stride (NBKT + 1)
#define MAXW 65               // LDS row stride (64 + 1 pad; 2-way = free)
#define NSTRIPE 32
#define XSTR 72               // LDS ushort row stride for W staging
#define BN_EPS 1e-5f

typedef __attribute__((ext_vector_type(8))) short short8;
typedef __attribute__((ext_vector_type(4))) float f32x4;

// ws layout:
//   Bkey   : N*32 u32 (bf16 key-packed x@W2)     12.8 MB
//   binned : NBINB*TILE u32 (tile-major, bucket-sorted within tile)  6.4 MB
//   Apb    : N*32 u32 (bf16-packed A')           12.8 MB
//   hpk    : N*32 u32 (bf16-packed h)            12.8 MB
//   tab    : NBINB*PSTR u32 (per-tile exclusive prefix)   1.23 MB
//   stripes: NSTRIPE*128 floats; finals: 128 floats

__device__ __forceinline__ float eluf(float x) {
    return x > 0.f ? x : (expf(x) - 1.f);
}
__device__ __forceinline__ float key32_to_f(unsigned k32) {
    unsigned k16 = k32 >> 16;
    unsigned u16 = (k16 & 0x8000u) ? (k16 & 0x7FFFu) : (~k16 & 0xFFFFu);
    return __uint_as_float(u16 << 16);
}
__device__ __forceinline__ unsigned bf16rne(float f) {
    unsigned u = __float_as_uint(f);
    return (u + 0x7FFFu + ((u >> 16) & 1u)) >> 16;
}
__device__ __forceinline__ float bf16lo_f(unsigned w) { return __uint_as_float((w & 0xFFFFu) << 16); }
__device__ __forceinline__ float bf16hi_f(unsigned w) { return __uint_as_float(w & 0xFFFF0000u); }

__device__ __forceinline__ short8 pack8(float4 a, float4 b) {
    short8 r;
    r[0] = (short)bf16rne(a.x); r[1] = (short)bf16rne(a.y);
    r[2] = (short)bf16rne(a.z); r[3] = (short)bf16rne(a.w);
    r[4] = (short)bf16rne(b.x); r[5] = (short)bf16rne(b.y);
    r[6] = (short)bf16rne(b.z); r[7] = (short)bf16rne(b.w);
    return r;
}

// Fused prep:
//  blocks [0,NBINB): histogram + scan + tab-row write + in-LDS-cursor placement
//                    (single kernel: no tab round-trip, second ei read is L2-hot)
//  blocks [NBINB,..): MFMA GEMM (bf16 16x16x32), co-resident with bin blocks.
__global__ __launch_bounds__(1024) void k_prep(const int* __restrict__ ei,
                                               const float* __restrict__ x,
                                               const float* __restrict__ W,
                                               const float* __restrict__ b,
                                               unsigned* __restrict__ tab,
                                               unsigned* __restrict__ binned,
                                               unsigned* __restrict__ Apb,
                                               unsigned* __restrict__ Bkey,
                                               float* __restrict__ stripes) {
    __shared__ __align__(16) unsigned char smem[18688];
    __shared__ unsigned ss[1024];
    int t = threadIdx.x;

    if (blockIdx.x < NBINB) {
        unsigned* hc = (unsigned*)smem;   // NBKT counters -> cursors (6252 B)
        int tile = blockIdx.x;
        int e0 = tile * TILE;
        int ecount = min(TILE, N_EDGES - e0);

        for (int i = t; i < NBKT; i += 1024) hc[i] = 0u;
        if (blockIdx.x == 0) {
            for (int i = t; i < NSTRIPE * 128; i += 1024) stripes[i] = 0.f;
        }
        __syncthreads();
        // pass 1: histogram of valid edges
        for (int i = t; i < ecount; i += 1024) {
            int src = ei[e0 + i];
            int dst = ei[N_EDGES + e0 + i];
            if ((unsigned)src < N_NODES && (unsigned)dst < N_NODES)
                atomicAdd(&hc[dst >> BKT_SHIFT], 1u);
        }
        __syncthreads();
        // scan: 2 elems/thread + Hillis-Steele over 1024 partial sums
        unsigned v0 = (2 * t < NBKT) ? hc[2 * t] : 0u;
        unsigned v1 = (2 * t + 1 < NBKT) ? hc[2 * t + 1] : 0u;
        unsigned s = v0 + v1;
        ss[t] = s;
        __syncthreads();
        for (int off = 1; off < 1024; off <<= 1) {
            unsigned v = (t >= off) ? ss[t - off] : 0u;
            __syncthreads();
            ss[t] += v;
            __syncthreads();
        }
        unsigned excl = ss[t] - s;
        unsigned* row = tab + (size_t)tile * PSTR;
        if (2 * t < NBKT) row[2 * t] = excl;
        if (2 * t + 1 < NBKT) row[2 * t + 1] = excl + v0;
        if (t == 1023) row[NBKT] = ss[1023];
        __syncthreads();
        // convert hc to exclusive-prefix cursors (in LDS, no tab re-read)
        if (2 * t < NBKT) hc[2 * t] = excl;
        if (2 * t + 1 < NBKT) hc[2 * t + 1] = excl + v0;
        __syncthreads();
        // pass 2: place (ei re-read is L2-hot; writes confined to own 32KB window)
        for (int i = t; i < ecount; i += 1024) {
            int src = ei[e0 + i];
            int dst = ei[N_EDGES + e0 + i];
            if ((unsigned)src >= N_NODES || (unsigned)dst >= N_NODES) continue;
            int bk = dst >> BKT_SHIFT;
            unsigned pos = atomicAdd(&hc[bk], 1u);
            binned[(size_t)tile * TILE + pos] =
                ((unsigned)(dst & (BKT_NODES - 1)) << 17) | (unsigned)src;
        }
    } else {
        // ---- gemm path: 256 nodes/block, 16 waves, bf16 16x16x32 MFMA ----
        unsigned short* WaT = (unsigned short*)smem;
        unsigned short* WbT = WaT + 64 * XSTR;
        float* biasS = (float*)(WbT + 64 * XSTR);
        int gb = blockIdx.x - NBINB;
        int base = gb * 256;

        for (int p = t; p < 4096; p += 1024) {
            int k = p >> 6, c = p & 63;
            float w1 = W[p];
            float w2 = W[4096 + p];
            WaT[c * XSTR + k] = (unsigned short)bf16rne(w1 - w2);
            WbT[c * XSTR + k] = (unsigned short)bf16rne(w2);
        }
        if (t < 64) biasS[t] = b[t];
        __syncthreads();

        int w = t >> 6;
        int l = t & 63;
        int ln = l & 15;
        int hi = l >> 4;

        short8 wa[4][2], wb[4][2];
#pragma unroll
        for (int nt = 0; nt < 4; ++nt)
#pragma unroll
            for (int h = 0; h < 2; ++h) {
                wa[nt][h] = *(const short8*)&WaT[(nt * 16 + ln) * XSTR + h * 32 + hi * 8];
                wb[nt][h] = *(const short8*)&WbT[(nt * 16 + ln) * XSTR + h * 32 + hi * 8];
            }

        int arow = base + w * 16 + ln;
        short8 af[2];
        if (arow < N_NODES) {
            const float4* xr = (const float4*)(x + (size_t)arow * 64);
#pragma unroll
            for (int h = 0; h < 2; ++h)
                af[h] = pack8(xr[h * 8 + hi * 2], xr[h * 8 + hi * 2 + 1]);
        } else {
#pragma unroll
            for (int h = 0; h < 2; ++h)
                af[h] = (short8){0, 0, 0, 0, 0, 0, 0, 0};
        }

        f32x4 acca[4], accb[4];
#pragma unroll
        for (int nt = 0; nt < 4; ++nt) {
            acca[nt] = (f32x4){0.f, 0.f, 0.f, 0.f};
            accb[nt] = (f32x4){0.f, 0.f, 0.f, 0.f};
#pragma unroll
            for (int h = 0; h < 2; ++h) {
                acca[nt] = __builtin_amdgcn_mfma_f32_16x16x32_bf16(af[h], wa[nt][h], acca[nt], 0, 0, 0);
                accb[nt] = __builtin_amdgcn_mfma_f32_16x16x32_bf16(af[h], wb[nt][h], accb[nt], 0, 0, 0);
            }
        }
#pragma unroll
        for (int nt = 0; nt < 4; ++nt) {
            int col = nt * 16 + ln;
            float bias = biasS[col];
            int cp = nt * 8 + (ln >> 1);
#pragma unroll
            for (int r = 0; r < 4; ++r) {
                int node = base + w * 16 + hi * 4 + r;
                unsigned a16 = bf16rne(acca[nt][r] + bias);
                unsigned aO = (unsigned)__shfl_xor((int)a16, 1, 64);
                unsigned r16 = bf16rne(accb[nt][r]);
                unsigned key16 = (r16 & 0x8000u) ? (~r16 & 0xFFFFu) : (r16 | 0x8000u);
                unsigned kO = (unsigned)__shfl_xor((int)key16, 1, 64);
                if (((l & 1) == 0) && node < N_NODES) {
                    Apb[(size_t)node * 32 + cp] = a16 | (aO << 16);
                    Bkey[(size_t)node * 32 + cp] = key16 | (kO << 16);
                }
            }
        }
    }
}

// One bucket per block (XCD-chunked swizzle). Reads its tab column (runs per
// tile), prefix-scans lengths, binary-searches run per edge, gathers Bkey
// (4 lanes/edge, 2 coalesced 64B lines), LDS atomicMax; finish + BN partials.
// (round-17 version verbatim — measured 44 us)
__global__ __launch_bounds__(256) void k_fused(const unsigned* __restrict__ tab,
                                               const unsigned* __restrict__ binned,
                                               const unsigned* __restrict__ Bkey,
                                               const unsigned* __restrict__ Apb,
                                               unsigned* __restrict__ hpk,
                                               float* __restrict__ stripes) {
    __shared__ __align__(16) unsigned mx[BKT_NODES * MAXW];  // 16640 B
    __shared__ unsigned rstart[NBINB];
    __shared__ unsigned rb[257];
    int t = threadIdx.x;
    // bijective XCD-chunked swizzle (nwg=1563, 8 XCDs, r=3)
    int orig = blockIdx.x;
    int xcd = orig & 7;
    int j = orig >> 3;
    int q = (xcd < 3 ? xcd * 196 : 3 * 196 + (xcd - 3) * 195) + j;
    int n0 = q * BKT_NODES;
    int nspan = min(BKT_NODES, N_NODES - n0);

    for (int i = t; i < BKT_NODES * MAXW; i += 256) mx[i] = 0u;

    unsigned own = 0;
    if (t < NBINB) {
        unsigned rs = tab[(size_t)t * PSTR + q];
        unsigned re = tab[(size_t)t * PSTR + q + 1];
        rstart[t] = rs;
        own = re - rs;
    }
    rb[t] = own;
    __syncthreads();
    for (int off = 1; off < 256; off <<= 1) {
        unsigned v = (t >= off) ? rb[t - off] : 0u;
        __syncthreads();
        rb[t] += v;
        __syncthreads();
    }
    unsigned excl = rb[t] - own;
    __syncthreads();
    rb[t] = excl;
    if (t == 255) rb[256] = excl + own;
    __syncthreads();
    unsigned cnt = rb[256];

    int ls = t & 3;
    for (unsigned idx = (unsigned)(t >> 2); idx < cnt; idx += 64) {
        unsigned lo = 0, hi = NBINB;
#pragma unroll
        for (int it = 0; it < 8; ++it) {
            unsigned mid = (lo + hi) >> 1;
            if (rb[mid] <= idx) lo = mid; else hi = mid;
        }
        unsigned p = binned[(size_t)lo * TILE + rstart[lo] + (idx - rb[lo])];
        unsigned src = p & 0x1FFFFu;
        unsigned dl = p >> 17;
        const uint4* bk = (const uint4*)(Bkey + (size_t)src * 32);
        uint4 w0 = bk[ls];
        uint4 w1 = bk[4 + ls];
        unsigned* row = mx + dl * MAXW;
        int s0 = ls * 8;
        atomicMax(&row[s0 + 0], w0.x << 16);
        atomicMax(&row[s0 + 1], w0.x & 0xFFFF0000u);
        atomicMax(&row[s0 + 2], w0.y << 16);
        atomicMax(&row[s0 + 3], w0.y & 0xFFFF0000u);
        atomicMax(&row[s0 + 4], w0.z << 16);
        atomicMax(&row[s0 + 5], w0.z & 0xFFFF0000u);
        atomicMax(&row[s0 + 6], w0.w << 16);
        atomicMax(&row[s0 + 7], w0.w & 0xFFFF0000u);
        int s1 = 32 + ls * 8;
        atomicMax(&row[s1 + 0], w1.x << 16);
        atomicMax(&row[s1 + 1], w1.x & 0xFFFF0000u);
        atomicMax(&row[s1 + 2], w1.y << 16);
        atomicMax(&row[s1 + 3], w1.y & 0xFFFF0000u);
        atomicMax(&row[s1 + 4], w1.z << 16);
        atomicMax(&row[s1 + 5], w1.z & 0xFFFF0000u);
        atomicMax(&row[s1 + 6], w1.w << 16);
        atomicMax(&row[s1 + 7], w1.w & 0xFFFF0000u);
    }
    __syncthreads();

    int lane4 = t & 15;
    int g = t >> 4;
    float4 s = make_float4(0.f, 0.f, 0.f, 0.f);
    float4 sq = make_float4(0.f, 0.f, 0.f, 0.f);
    for (int nl = g; nl < nspan; nl += 16) {
        int n = n0 + nl;
        const unsigned* row = mx + nl * MAXW + lane4 * 4;
        unsigned k0 = row[0], k1 = row[1], k2 = row[2], k3 = row[3];
        uint2 ap = *reinterpret_cast<const uint2*>(Apb + (size_t)n * 32 + lane4 * 2);
        float h0 = (k0 == 0u) ? 0.f : eluf(bf16lo_f(ap.x) + key32_to_f(k0));
        float h1 = (k1 == 0u) ? 0.f : eluf(bf16hi_f(ap.x) + key32_to_f(k1));
        float h2 = (k2 == 0u) ? 0.f : eluf(bf16lo_f(ap.y) + key32_to_f(k2));
        float h3 = (k3 == 0u) ? 0.f : eluf(bf16hi_f(ap.y) + key32_to_f(k3));
        unsigned q0 = bf16rne(h0), q1 = bf16rne(h1), q2 = bf16rne(h2), q3 = bf16rne(h3);
        uint2 hp;
        hp.x = q0 | (q1 << 16);
        hp.y = q2 | (q3 << 16);
        *reinterpret_cast<uint2*>(hpk + (size_t)n * 32 + lane4 * 2) = hp;
        float f0 = __uint_as_float(q0 << 16), f1 = __uint_as_float(q1 << 16);
        float f2 = __uint_as_float(q2 << 16), f3 = __uint_as_float(q3 << 16);
        s.x += f0; s.y += f1; s.z += f2; s.w += f3;
        sq.x += f0 * f0; sq.y += f1 * f1; sq.z += f2 * f2; sq.w += f3 * f3;
    }
    __syncthreads();

    float4* lsum = (float4*)mx;
    float4* lqum = lsum + 256;
    lsum[t] = s;
    lqum[t] = sq;
    __syncthreads();
#pragma unroll
    for (int off = 8; off >= 1; off >>= 1) {
        if (g < off) {
            int o = t + off * 16;
            lsum[t].x += lsum[o].x; lsum[t].y += lsum[o].y; lsum[t].z += lsum[o].z; lsum[t].w += lsum[o].w;
            lqum[t].x += lqum[o].x; lqum[t].y += lqum[o].y; lqum[t].z += lqum[o].z; lqum[t].w += lqum[o].w;
        }
        __syncthreads();
    }
    if (g == 0) {
        float* sb = stripes + (q & (NSTRIPE - 1)) * 128;
        int c4 = lane4 * 4;
        atomicAdd(&sb[c4 + 0], lsum[t].x);
        atomicAdd(&sb[c4 + 1], lsum[t].y);
        atomicAdd(&sb[c4 + 2], lsum[t].z);
        atomicAdd(&sb[c4 + 3], lsum[t].w);
        atomicAdd(&sb[64 + c4 + 0], lqum[t].x);
        atomicAdd(&sb[64 + c4 + 1], lqum[t].y);
        atomicAdd(&sb[64 + c4 + 2], lqum[t].z);
        atomicAdd(&sb[64 + c4 + 3], lqum[t].w);
    }
}

// fold 32 stripes -> 128 finals
__global__ __launch_bounds__(128) void k_reduce(const float* __restrict__ stripes,
                                                float* __restrict__ finals) {
    int t = threadIdx.x;
    float acc = 0.f;
#pragma unroll
    for (int s = 0; s < NSTRIPE; ++s) acc += stripes[s * 128 + t];
    finals[t] = acc;
}

// out = gamma*(h-mean)*rsqrt(var+eps)+beta; reads bf16-packed h, writes f32
__global__ __launch_bounds__(256) void k_bn(const uint2* __restrict__ hpk2,
                                            const float* __restrict__ finals,
                                            const float* __restrict__ gamma,
                                            const float* __restrict__ beta,
                                            float4* __restrict__ out4) {
    size_t i = (size_t)blockIdx.x * blockDim.x + threadIdx.x;
    size_t stride = (size_t)gridDim.x * blockDim.x;
    const float invN = 1.f / (float)N_NODES;
    size_t total4 = (size_t)N_NODES * C / 4;
    for (size_t p = i; p < total4; p += stride) {
        int c4 = (int)(p & 15) * 4;
        uint2 hp = hpk2[p];
        float hx = bf16lo_f(hp.x), hy = bf16hi_f(hp.x);
        float hz = bf16lo_f(hp.y), hw = bf16hi_f(hp.y);
        float4 o;
        float m, v, inv;
        m = finals[c4 + 0] * invN; v = finals[64 + c4 + 0] * invN - m * m; inv = rsqrtf(v + BN_EPS);
        o.x = gamma[c4 + 0] * (hx - m) * inv + beta[c4 + 0];
        m = finals[c4 + 1] * invN; v = finals[64 + c4 + 1] * invN - m * m; inv = rsqrtf(v + BN_EPS);
        o.y = gamma[c4 + 1] * (hy - m) * inv + beta[c4 + 1];
        m = finals[c4 + 2] * invN; v = finals[64 + c4 + 2] * invN - m * m; inv = rsqrtf(v + BN_EPS);
        o.z = gamma[c4 + 2] * (hz - m) * inv + beta[c4 + 2];
        m = finals[c4 + 3] * invN; v = finals[64 + c4 + 3] * invN - m * m; inv = rsqrtf(v + BN_EPS);
        o.w = gamma[c4 + 3] * (hw - m) * inv + beta[c4 + 3];
        out4[p] = o;
    }
}

extern "C" void kernel_launch(void* const* d_in, const int* in_sizes, int n_in,
                              void* d_out, int out_size, void* d_ws, size_t ws_size,
                              hipStream_t stream) {
    const float* x = (const float*)d_in[0];
    const int* ei = (const int*)d_in[1];  // int32 per harness contract
    const float* W = (const float*)d_in[2];
    const float* b = (const float*)d_in[3];
    const float* gamma = (const float*)d_in[4];
    const float* beta = (const float*)d_in[5];
    float* out = (float*)d_out;

    char* ws = (char*)d_ws;
    unsigned* Bkey = (unsigned*)ws;                                      // 12.8 MB
    unsigned* binned = Bkey + (size_t)N_NODES * 32;                      // 6.43 MB
    unsigned* Apb = binned + (size_t)NBINB * TILE;                       // 12.8 MB
    unsigned* hpk = Apb + (size_t)N_NODES * 32;                          // 12.8 MB
    unsigned* tab = hpk + (size_t)N_NODES * 32;                          // 1.23 MB
    float* stripes = (float*)(tab + (size_t)NBINB * PSTR);
    float* finals = stripes + NSTRIPE * 128;

    k_prep<<<NBINB + NGEMB, 1024, 0, stream>>>(ei, x, W, b, tab, binned, Apb, Bkey, stripes);
    k_fused<<<NBKT, 256, 0, stream>>>(tab, binned, Bkey, Apb, hpk, stripes);
    k_reduce<<<1, 128, 0, stream>>>(stripes, finals);
    k_bn<<<2048, 256, 0, stream>>>((const uint2*)hpk, finals, gamma, beta, (float4*)out);
}